// Round 1
// baseline (480.803 us; speedup 1.0000x reference)
//
#include <hip/hip_runtime.h>
#include <math.h>

// DVGO volume-rendering forward.
// One 64-lane wave per ray (8192 rays = 8192 waves = 32 waves/CU at full occ).
// Lanes cover 64 consecutive samples; 9 chunks span S=558. Transmittance
// cumprod = wave prefix-product (shfl_up) + carry broadcast.

namespace {
constexpr int   kR   = 8192;
constexpr int   kS   = 558;          // int(norm([161,161,161])/0.5)+1
constexpr int   kG   = 160;
constexpr int   kG3  = kG * kG * kG;
constexpr float kNear = 0.05f;
constexpr float kFar  = 6.0f;
constexpr float kStepWorld = 0.5f * (2.0f / 160.0f);  // STEPSIZE * VOXEL_SIZE
// log(1/(1-1e-6) - 1) computed in double, rounded to float
constexpr float kActShift = (float)-13.815509557963774;
}

__device__ __forceinline__ float sigmoidf_(float x) {
  return 1.0f / (1.0f + expf(-x));
}

__global__ __launch_bounds__(256) void dvgo_fwd(
    const float* __restrict__ rays_o,
    const float* __restrict__ rays_d,
    const float* __restrict__ jitter,
    const int*   __restrict__ em_modes,
    const float* __restrict__ density,
    const float* __restrict__ off_c,
    const float* __restrict__ emo_c,
    float* __restrict__ out)
{
  const int tid  = blockIdx.x * blockDim.x + threadIdx.x;
  const int ray  = tid >> 6;
  const int lane = tid & 63;
  if (ray >= kR) return;

  // ---- per-ray setup (redundant in every lane; cheap) ----
  const float ox = rays_o[ray * 3 + 0];
  const float oy = rays_o[ray * 3 + 1];
  const float oz = rays_o[ray * 3 + 2];
  const float dx = rays_d[ray * 3 + 0];
  const float dy = rays_d[ray * 3 + 1];
  const float dz = rays_d[ray * 3 + 2];
  const float jit = jitter[ray];
  const bool  on  = (em_modes[ray] == 1);

  const float vx = (dx == 0.0f) ? 1e-6f : dx;
  const float vy = (dy == 0.0f) ? 1e-6f : dy;
  const float vz = (dz == 0.0f) ? 1e-6f : dz;
  const float rax = ( 1.0f - ox) / vx, rbx = (-1.0f - ox) / vx;
  const float ray_a = ( 1.0f - oy) / vy, rby = (-1.0f - oy) / vy;
  const float raz = ( 1.0f - oz) / vz, rbz = (-1.0f - oz) / vz;
  float tmin = fmaxf(fmaxf(fminf(rax, rbx), fminf(ray_a, rby)), fminf(raz, rbz));
  float tmax = fminf(fminf(fmaxf(rax, rbx), fmaxf(ray_a, rby)), fmaxf(raz, rbz));
  tmin = fminf(fmaxf(tmin, kNear), kFar);
  tmax = fminf(fmaxf(tmax, kNear), kFar);
  const bool  ray_out = (tmax <= tmin);
  const float dnorm = sqrtf(dx * dx + dy * dy + dz * dz);
  const float stepc = kStepWorld / dnorm;

  // ---- output layout (tuple concatenated flat) ----
  float* out_ainv = out;                           // [R, S+1]
  float* out_w    = out + (size_t)kR * (kS + 1);   // [R, S]
  float* out_last = out_w + (size_t)kR * kS;       // [R, 1]
  float* out_rgb  = out_last + kR;                 // [R, S, 3]
  float* out_rm   = out_rgb + (size_t)kR * kS * 3; // [R, 3]

  if (lane == 0) out_ainv[(size_t)ray * (kS + 1)] = 1.0f;

  float carry = 1.0f;
  float accr = 0.0f, accg = 0.0f, accb = 0.0f;

  #pragma unroll 1
  for (int chunk = 0; chunk < (kS + 63) / 64; ++chunk) {
    const int  s      = chunk * 64 + lane;
    const bool active = (s < kS);

    const float t  = tmin + stepc * ((float)s + jit);
    const float px = fmaf(dx, t, ox);
    const float py = fmaf(dy, t, oy);
    const float pz = fmaf(dz, t, oz);
    const bool inb = (px >= -1.0f) & (px <= 1.0f) &
                     (py >= -1.0f) & (py <= 1.0f) &
                     (pz >= -1.0f) & (pz <= 1.0f);
    const bool masked = ray_out || !inb;

    // voxel-space coords, align_corners=True
    const float fx = (px + 1.0f) * 0.5f * (float)(kG - 1);
    const float fy = (py + 1.0f) * 0.5f * (float)(kG - 1);
    const float fz = (pz + 1.0f) * 0.5f * (float)(kG - 1);
    const int ix = (int)floorf(fx);
    const int iy = (int)floorf(fy);
    const int iz = (int)floorf(fz);
    const float wx = fx - (float)ix;
    const float wy = fy - (float)iy;
    const float wz = fz - (float)iz;

    float dsum = 0.0f;
    float o0 = 0.0f, o1 = 0.0f, o2 = 0.0f;
    float e0 = 0.0f, e1 = 0.0f, e2 = 0.0f;

    // any corner valid? (corner coords are ix..ix+1 etc.)
    const bool any = active &&
        (ix >= -1) && (ix <= kG - 1) &&
        (iy >= -1) && (iy <= kG - 1) &&
        (iz >= -1) && (iz <= kG - 1);
    if (any) {
      #pragma unroll
      for (int c = 0; c < 8; ++c) {
        const int ddx = (c >> 2) & 1, ddy = (c >> 1) & 1, ddz = c & 1;
        const int cx = ix + ddx, cy = iy + ddy, cz = iz + ddz;
        const bool valid = ((unsigned)cx < (unsigned)kG) &
                           ((unsigned)cy < (unsigned)kG) &
                           ((unsigned)cz < (unsigned)kG);
        const float w = (ddx ? wx : 1.0f - wx) *
                        (ddy ? wy : 1.0f - wy) *
                        (ddz ? wz : 1.0f - wz);
        const float wv = valid ? w : 0.0f;
        const int gx = min(max(cx, 0), kG - 1);
        const int gy = min(max(cy, 0), kG - 1);
        const int gz = min(max(cz, 0), kG - 1);
        const int gi = (gx * kG + gy) * kG + gz;
        dsum = fmaf(wv, density[gi], dsum);
        o0 = fmaf(wv, off_c[gi], o0);
        o1 = fmaf(wv, off_c[gi + kG3], o1);
        o2 = fmaf(wv, off_c[gi + 2 * kG3], o2);
        if (on) {  // wave-uniform: one ray per wave
          e0 = fmaf(wv, emo_c[gi], e0);
          e1 = fmaf(wv, emo_c[gi + kG3], e1);
          e2 = fmaf(wv, emo_c[gi + 2 * kG3], e2);
        }
      }
    }

    // alpha from density (masked samples -> 0)
    float alpha = 0.0f;
    if (active && !masked) {
      const float x  = dsum + kActShift;
      const float sp = fmaxf(x, 0.0f) + log1pf(expf(-fabsf(x)));  // softplus
      alpha = 1.0f - expf(-sp * 0.5f);
    }
    float p = fmaxf(1.0f - alpha, 1e-10f);
    if (!active) p = 1.0f;

    // wave-wide inclusive prefix product
    float incl = p;
    #pragma unroll
    for (int o = 1; o < 64; o <<= 1) {
      const float n = __shfl_up(incl, o, 64);
      if (lane >= o) incl *= n;
    }
    float excl = __shfl_up(incl, 1, 64);
    if (lane == 0) excl = 1.0f;
    const float ainv_prev = carry * excl;   // alphainv_cum[s]
    const float ainv_next = carry * incl;   // alphainv_cum[s+1]
    const float wgt = alpha * ainv_prev;
    carry *= __shfl(incl, 63, 64);          // uniform across wave

    // colors (zero-padding sampler -> sigmoid(0)=0.5 when fully outside)
    float rr = sigmoidf_(o0);
    float gg = sigmoidf_(o1);
    float bb = sigmoidf_(o2);
    if (on) {
      rr += sigmoidf_(e0);
      gg += sigmoidf_(e1);
      bb += sigmoidf_(e2);
    }

    if (active) {
      out_ainv[(size_t)ray * (kS + 1) + s + 1] = ainv_next;
      out_w[(size_t)ray * kS + s] = wgt;
      const size_t rb = ((size_t)ray * kS + s) * 3;
      out_rgb[rb + 0] = rr;
      out_rgb[rb + 1] = gg;
      out_rgb[rb + 2] = bb;
      accr = fmaf(wgt, rr, accr);
      accg = fmaf(wgt, gg, accg);
      accb = fmaf(wgt, bb, accb);
    }
  }

  // wave reduction for rgb_marched
  #pragma unroll
  for (int o = 32; o > 0; o >>= 1) {
    accr += __shfl_xor(accr, o, 64);
    accg += __shfl_xor(accg, o, 64);
    accb += __shfl_xor(accb, o, 64);
  }
  if (lane == 0) {
    out_last[ray] = carry;
    out_rm[(size_t)ray * 3 + 0] = accr;
    out_rm[(size_t)ray * 3 + 1] = accg;
    out_rm[(size_t)ray * 3 + 2] = accb;
  }
}

extern "C" void kernel_launch(void* const* d_in, const int* in_sizes, int n_in,
                              void* d_out, int out_size, void* d_ws, size_t ws_size,
                              hipStream_t stream) {
  const float* rays_o  = (const float*)d_in[0];
  const float* rays_d  = (const float*)d_in[1];
  const float* jitter  = (const float*)d_in[2];
  const int*   em      = (const int*)d_in[3];
  const float* density = (const float*)d_in[4];
  const float* off_c   = (const float*)d_in[5];
  const float* emo_c   = (const float*)d_in[6];
  float* out = (float*)d_out;

  const int threads = 256;                 // 4 waves = 4 rays per block
  const int blocks  = (kR * 64) / threads; // 2048 blocks
  hipLaunchKernelGGL(dvgo_fwd, dim3(blocks), dim3(threads), 0, stream,
                     rays_o, rays_d, jitter, em, density, off_c, emo_c, out);
}

// Round 2
// 288.720 us; speedup vs baseline: 1.6653x; 1.6653x over previous
//
#include <hip/hip_runtime.h>
#include <math.h>

// DVGO volume-rendering forward, round 2.
// Change vs round 1: repack the 7 grid channels (density, off_rgb, emo_rgb)
// from planar [C][X][Y][Z] into interleaved [X][Y][Z][8] (AoS, 1 pad chan)
// in d_ws. One trilinear corner then touches ONE cache line (32B aligned)
// instead of seven. Round-1 rocprof: FETCH_SIZE 1.05 GB vs ~115 MB of grid
// -> ~9x over-fetch was the entire kernel duration (VALUBusy 11%).

namespace {
constexpr int   kR   = 8192;
constexpr int   kS   = 558;
constexpr int   kG   = 160;
constexpr int   kG3  = kG * kG * kG;
constexpr float kNear = 0.05f;
constexpr float kFar  = 6.0f;
constexpr float kStepWorld = 0.5f * (2.0f / 160.0f);  // STEPSIZE * VOXEL_SIZE
constexpr float kActShift = (float)-13.815509557963774; // log(1/(1-1e-6)-1)
constexpr size_t kPackedBytes = (size_t)kG3 * 8 * sizeof(float); // 131 MB
}

__device__ __forceinline__ float sigmoidf_(float x) {
  return 1.0f / (1.0f + expf(-x));
}

// ---- repack: planar 7-channel -> interleaved float8 per voxel ----
__global__ __launch_bounds__(256) void repack_grids(
    const float* __restrict__ density,
    const float* __restrict__ off_c,
    const float* __restrict__ emo_c,
    float4* __restrict__ packed)  // [kG3 * 2] float4
{
  const int v = blockIdx.x * blockDim.x + threadIdx.x;
  if (v >= kG3) return;
  float4 a, b;
  a.x = density[v];
  a.y = off_c[v];
  a.z = off_c[v + kG3];
  a.w = off_c[v + 2 * kG3];
  b.x = emo_c[v];
  b.y = emo_c[v + kG3];
  b.z = emo_c[v + 2 * kG3];
  b.w = 0.0f;
  packed[(size_t)v * 2 + 0] = a;
  packed[(size_t)v * 2 + 1] = b;
}

// ---- main: one 64-lane wave per ray ----
template <bool PACKED>
__global__ __launch_bounds__(256) void dvgo_fwd(
    const float* __restrict__ rays_o,
    const float* __restrict__ rays_d,
    const float* __restrict__ jitter,
    const int*   __restrict__ em_modes,
    const float* __restrict__ density,
    const float* __restrict__ off_c,
    const float* __restrict__ emo_c,
    const float4* __restrict__ packed,
    float* __restrict__ out)
{
  const int tid  = blockIdx.x * blockDim.x + threadIdx.x;
  const int ray  = tid >> 6;
  const int lane = tid & 63;
  if (ray >= kR) return;

  const float ox = rays_o[ray * 3 + 0];
  const float oy = rays_o[ray * 3 + 1];
  const float oz = rays_o[ray * 3 + 2];
  const float dx = rays_d[ray * 3 + 0];
  const float dy = rays_d[ray * 3 + 1];
  const float dz = rays_d[ray * 3 + 2];
  const float jit = jitter[ray];
  const bool  on  = (em_modes[ray] == 1);

  const float vx = (dx == 0.0f) ? 1e-6f : dx;
  const float vy = (dy == 0.0f) ? 1e-6f : dy;
  const float vz = (dz == 0.0f) ? 1e-6f : dz;
  const float rax = ( 1.0f - ox) / vx, rbx = (-1.0f - ox) / vx;
  const float ray_a = ( 1.0f - oy) / vy, rby = (-1.0f - oy) / vy;
  const float raz = ( 1.0f - oz) / vz, rbz = (-1.0f - oz) / vz;
  float tmin = fmaxf(fmaxf(fminf(rax, rbx), fminf(ray_a, rby)), fminf(raz, rbz));
  float tmax = fminf(fminf(fmaxf(rax, rbx), fmaxf(ray_a, rby)), fmaxf(raz, rbz));
  tmin = fminf(fmaxf(tmin, kNear), kFar);
  tmax = fminf(fmaxf(tmax, kNear), kFar);
  const bool  ray_out = (tmax <= tmin);
  const float dnorm = sqrtf(dx * dx + dy * dy + dz * dz);
  const float stepc = kStepWorld / dnorm;

  float* out_ainv = out;                           // [R, S+1]
  float* out_w    = out + (size_t)kR * (kS + 1);   // [R, S]
  float* out_last = out_w + (size_t)kR * kS;       // [R, 1]
  float* out_rgb  = out_last + kR;                 // [R, S, 3]
  float* out_rm   = out_rgb + (size_t)kR * kS * 3; // [R, 3]

  if (lane == 0) out_ainv[(size_t)ray * (kS + 1)] = 1.0f;

  float carry = 1.0f;
  float accr = 0.0f, accg = 0.0f, accb = 0.0f;

  #pragma unroll 1
  for (int chunk = 0; chunk < (kS + 63) / 64; ++chunk) {
    const int  s      = chunk * 64 + lane;
    const bool active = (s < kS);

    const float t  = tmin + stepc * ((float)s + jit);
    const float px = fmaf(dx, t, ox);
    const float py = fmaf(dy, t, oy);
    const float pz = fmaf(dz, t, oz);
    const bool inb = (px >= -1.0f) & (px <= 1.0f) &
                     (py >= -1.0f) & (py <= 1.0f) &
                     (pz >= -1.0f) & (pz <= 1.0f);
    const bool masked = ray_out || !inb;

    const float fx = (px + 1.0f) * 0.5f * (float)(kG - 1);
    const float fy = (py + 1.0f) * 0.5f * (float)(kG - 1);
    const float fz = (pz + 1.0f) * 0.5f * (float)(kG - 1);
    const int ix = (int)floorf(fx);
    const int iy = (int)floorf(fy);
    const int iz = (int)floorf(fz);
    const float wx = fx - (float)ix;
    const float wy = fy - (float)iy;
    const float wz = fz - (float)iz;

    float dsum = 0.0f;
    float o0 = 0.0f, o1 = 0.0f, o2 = 0.0f;
    float e0 = 0.0f, e1 = 0.0f, e2 = 0.0f;

    const bool any = active &&
        (ix >= -1) && (ix <= kG - 1) &&
        (iy >= -1) && (iy <= kG - 1) &&
        (iz >= -1) && (iz <= kG - 1);
    if (any) {
      #pragma unroll
      for (int c = 0; c < 8; ++c) {
        const int ddx = (c >> 2) & 1, ddy = (c >> 1) & 1, ddz = c & 1;
        const int cx = ix + ddx, cy = iy + ddy, cz = iz + ddz;
        const bool valid = ((unsigned)cx < (unsigned)kG) &
                           ((unsigned)cy < (unsigned)kG) &
                           ((unsigned)cz < (unsigned)kG);
        const float w = (ddx ? wx : 1.0f - wx) *
                        (ddy ? wy : 1.0f - wy) *
                        (ddz ? wz : 1.0f - wz);
        const float wv = valid ? w : 0.0f;
        const int gx = min(max(cx, 0), kG - 1);
        const int gy = min(max(cy, 0), kG - 1);
        const int gz = min(max(cz, 0), kG - 1);
        const int gi = (gx * kG + gy) * kG + gz;
        if (PACKED) {
          const float4 a = packed[(size_t)gi * 2];
          dsum = fmaf(wv, a.x, dsum);
          o0   = fmaf(wv, a.y, o0);
          o1   = fmaf(wv, a.z, o1);
          o2   = fmaf(wv, a.w, o2);
          if (on) {
            const float4 b = packed[(size_t)gi * 2 + 1];
            e0 = fmaf(wv, b.x, e0);
            e1 = fmaf(wv, b.y, e1);
            e2 = fmaf(wv, b.z, e2);
          }
        } else {
          dsum = fmaf(wv, density[gi], dsum);
          o0 = fmaf(wv, off_c[gi], o0);
          o1 = fmaf(wv, off_c[gi + kG3], o1);
          o2 = fmaf(wv, off_c[gi + 2 * kG3], o2);
          if (on) {
            e0 = fmaf(wv, emo_c[gi], e0);
            e1 = fmaf(wv, emo_c[gi + kG3], e1);
            e2 = fmaf(wv, emo_c[gi + 2 * kG3], e2);
          }
        }
      }
    }

    float alpha = 0.0f;
    if (active && !masked) {
      const float x  = dsum + kActShift;
      const float sp = fmaxf(x, 0.0f) + log1pf(expf(-fabsf(x)));
      alpha = 1.0f - expf(-sp * 0.5f);
    }
    float p = fmaxf(1.0f - alpha, 1e-10f);
    if (!active) p = 1.0f;

    float incl = p;
    #pragma unroll
    for (int o = 1; o < 64; o <<= 1) {
      const float n = __shfl_up(incl, o, 64);
      if (lane >= o) incl *= n;
    }
    float excl = __shfl_up(incl, 1, 64);
    if (lane == 0) excl = 1.0f;
    const float ainv_prev = carry * excl;
    const float ainv_next = carry * incl;
    const float wgt = alpha * ainv_prev;
    carry *= __shfl(incl, 63, 64);

    float rr = sigmoidf_(o0);
    float gg = sigmoidf_(o1);
    float bb = sigmoidf_(o2);
    if (on) {
      rr += sigmoidf_(e0);
      gg += sigmoidf_(e1);
      bb += sigmoidf_(e2);
    }

    if (active) {
      out_ainv[(size_t)ray * (kS + 1) + s + 1] = ainv_next;
      out_w[(size_t)ray * kS + s] = wgt;
      const size_t rb = ((size_t)ray * kS + s) * 3;
      out_rgb[rb + 0] = rr;
      out_rgb[rb + 1] = gg;
      out_rgb[rb + 2] = bb;
      accr = fmaf(wgt, rr, accr);
      accg = fmaf(wgt, gg, accg);
      accb = fmaf(wgt, bb, accb);
    }
  }

  #pragma unroll
  for (int o = 32; o > 0; o >>= 1) {
    accr += __shfl_xor(accr, o, 64);
    accg += __shfl_xor(accg, o, 64);
    accb += __shfl_xor(accb, o, 64);
  }
  if (lane == 0) {
    out_last[ray] = carry;
    out_rm[(size_t)ray * 3 + 0] = accr;
    out_rm[(size_t)ray * 3 + 1] = accg;
    out_rm[(size_t)ray * 3 + 2] = accb;
  }
}

extern "C" void kernel_launch(void* const* d_in, const int* in_sizes, int n_in,
                              void* d_out, int out_size, void* d_ws, size_t ws_size,
                              hipStream_t stream) {
  const float* rays_o  = (const float*)d_in[0];
  const float* rays_d  = (const float*)d_in[1];
  const float* jitter  = (const float*)d_in[2];
  const int*   em      = (const int*)d_in[3];
  const float* density = (const float*)d_in[4];
  const float* off_c   = (const float*)d_in[5];
  const float* emo_c   = (const float*)d_in[6];
  float* out = (float*)d_out;

  const int threads = 256;
  const int blocks  = (kR * 64) / threads;  // 2048

  if (ws_size >= kPackedBytes) {
    float4* packed = (float4*)d_ws;
    hipLaunchKernelGGL(repack_grids, dim3((kG3 + 255) / 256), dim3(256), 0,
                       stream, density, off_c, emo_c, packed);
    hipLaunchKernelGGL(dvgo_fwd<true>, dim3(blocks), dim3(threads), 0, stream,
                       rays_o, rays_d, jitter, em, density, off_c, emo_c,
                       packed, out);
  } else {
    hipLaunchKernelGGL(dvgo_fwd<false>, dim3(blocks), dim3(threads), 0, stream,
                       rays_o, rays_d, jitter, em, density, off_c, emo_c,
                       (const float4*)nullptr, out);
  }
}

// Round 3
// 264.515 us; speedup vs baseline: 1.8177x; 1.0915x over previous
//
#include <hip/hip_runtime.h>
#include <math.h>

// DVGO volume-rendering forward, round 3.
// vs round 2:
//  - grid packed as 8 x bf16 = 16 B/voxel (uint4): one corner = ONE
//    global_load_dwordx4 with all 7 channels (off-rays read 8 B only).
//    Halves compulsory grid HBM fetch (124 -> ~65 MB) and repack write.
//  - interior fast path: all-8-corners-valid samples skip clamp/valid
//    logic (single base index + constant offsets). Border samples keep
//    the general path; split is nearly wave-uniform along a ray.
// bf16 precision: rel ~2^-9 -> abs output err ~1e-3 << 2.2e-2 threshold.

namespace {
constexpr int   kR   = 8192;
constexpr int   kS   = 558;
constexpr int   kG   = 160;
constexpr int   kG2  = kG * kG;
constexpr int   kG3  = kG * kG * kG;
constexpr float kNear = 0.05f;
constexpr float kFar  = 6.0f;
constexpr float kStepWorld = 0.5f * (2.0f / 160.0f);  // STEPSIZE * VOXEL_SIZE
constexpr float kActShift = (float)-13.815509557963774; // log(1/(1-1e-6)-1)
constexpr size_t kPackedBytes = (size_t)kG3 * 16;       // 65.5 MB
}

__device__ __forceinline__ float sigmoidf_(float x) {
  return 1.0f / (1.0f + expf(-x));
}
__device__ __forceinline__ float bf_lo(unsigned int u) {
  union { unsigned int i; float f; } x; x.i = u << 16; return x.f;
}
__device__ __forceinline__ float bf_hi(unsigned int u) {
  union { unsigned int i; float f; } x; x.i = u & 0xffff0000u; return x.f;
}
__device__ __forceinline__ unsigned short f2bf(float f) {
  // round-to-nearest-even bf16
  union { float f; unsigned int i; } x; x.f = f;
  unsigned int lsb = (x.i >> 16) & 1u;
  return (unsigned short)((x.i + 0x7fffu + lsb) >> 16);
}

// ---- repack: planar 7-channel f32 -> 8 x bf16 per voxel (16 B) ----
__global__ __launch_bounds__(256) void repack_grids(
    const float* __restrict__ density,
    const float* __restrict__ off_c,
    const float* __restrict__ emo_c,
    uint4* __restrict__ packed)  // [kG3]
{
  const int v = blockIdx.x * blockDim.x + threadIdx.x;
  if (v >= kG3) return;
  const unsigned int d  = f2bf(density[v]);
  const unsigned int f0 = f2bf(off_c[v]);
  const unsigned int f1 = f2bf(off_c[v + kG3]);
  const unsigned int f2 = f2bf(off_c[v + 2 * kG3]);
  const unsigned int e0 = f2bf(emo_c[v]);
  const unsigned int e1 = f2bf(emo_c[v + kG3]);
  const unsigned int e2 = f2bf(emo_c[v + 2 * kG3]);
  uint4 q;
  q.x = d  | (f0 << 16);   // lo=dens, hi=off0
  q.y = f1 | (f2 << 16);   // lo=off1, hi=off2
  q.z = e0 | (e1 << 16);   // lo=emo0, hi=emo1
  q.w = e2;                // lo=emo2, hi=pad
  packed[v] = q;
}

// ---- main: one 64-lane wave per ray ----
__global__ __launch_bounds__(256) void dvgo_fwd(
    const float* __restrict__ rays_o,
    const float* __restrict__ rays_d,
    const float* __restrict__ jitter,
    const int*   __restrict__ em_modes,
    const uint2* __restrict__ packed2,  // 2 x uint2 per voxel
    float* __restrict__ out)
{
  const int tid  = blockIdx.x * blockDim.x + threadIdx.x;
  const int ray  = tid >> 6;
  const int lane = tid & 63;
  if (ray >= kR) return;

  const float ox = rays_o[ray * 3 + 0];
  const float oy = rays_o[ray * 3 + 1];
  const float oz = rays_o[ray * 3 + 2];
  const float dx = rays_d[ray * 3 + 0];
  const float dy = rays_d[ray * 3 + 1];
  const float dz = rays_d[ray * 3 + 2];
  const float jit = jitter[ray];
  const bool  on  = (em_modes[ray] == 1);

  const float vx = (dx == 0.0f) ? 1e-6f : dx;
  const float vy = (dy == 0.0f) ? 1e-6f : dy;
  const float vz = (dz == 0.0f) ? 1e-6f : dz;
  const float rax = ( 1.0f - ox) / vx, rbx = (-1.0f - ox) / vx;
  const float ray_a = ( 1.0f - oy) / vy, rby = (-1.0f - oy) / vy;
  const float raz = ( 1.0f - oz) / vz, rbz = (-1.0f - oz) / vz;
  float tmin = fmaxf(fmaxf(fminf(rax, rbx), fminf(ray_a, rby)), fminf(raz, rbz));
  float tmax = fminf(fminf(fmaxf(rax, rbx), fmaxf(ray_a, rby)), fmaxf(raz, rbz));
  tmin = fminf(fmaxf(tmin, kNear), kFar);
  tmax = fminf(fmaxf(tmax, kNear), kFar);
  const bool  ray_out = (tmax <= tmin);
  const float dnorm = sqrtf(dx * dx + dy * dy + dz * dz);
  const float stepc = kStepWorld / dnorm;

  float* out_ainv = out;                           // [R, S+1]
  float* out_w    = out + (size_t)kR * (kS + 1);   // [R, S]
  float* out_last = out_w + (size_t)kR * kS;       // [R, 1]
  float* out_rgb  = out_last + kR;                 // [R, S, 3]
  float* out_rm   = out_rgb + (size_t)kR * kS * 3; // [R, 3]

  if (lane == 0) out_ainv[(size_t)ray * (kS + 1)] = 1.0f;

  float carry = 1.0f;
  float accr = 0.0f, accg = 0.0f, accb = 0.0f;

  #pragma unroll 1
  for (int chunk = 0; chunk < (kS + 63) / 64; ++chunk) {
    const int  s      = chunk * 64 + lane;
    const bool active = (s < kS);

    const float t  = tmin + stepc * ((float)s + jit);
    const float px = fmaf(dx, t, ox);
    const float py = fmaf(dy, t, oy);
    const float pz = fmaf(dz, t, oz);
    const bool inb = (px >= -1.0f) & (px <= 1.0f) &
                     (py >= -1.0f) & (py <= 1.0f) &
                     (pz >= -1.0f) & (pz <= 1.0f);
    const bool masked = ray_out || !inb;

    const float fx = (px + 1.0f) * 0.5f * (float)(kG - 1);
    const float fy = (py + 1.0f) * 0.5f * (float)(kG - 1);
    const float fz = (pz + 1.0f) * 0.5f * (float)(kG - 1);
    const int ix = (int)floorf(fx);
    const int iy = (int)floorf(fy);
    const int iz = (int)floorf(fz);
    const float wx = fx - (float)ix;
    const float wy = fy - (float)iy;
    const float wz = fz - (float)iz;

    // 8 trilinear weights
    const float x0 = 1.0f - wx, y0 = 1.0f - wy, z0 = 1.0f - wz;
    const float wxy00 = x0 * y0, wxy01 = x0 * wy;
    const float wxy10 = wx * y0, wxy11 = wx * wy;
    float w8[8];
    w8[0] = wxy00 * z0; w8[1] = wxy00 * wz;
    w8[2] = wxy01 * z0; w8[3] = wxy01 * wz;
    w8[4] = wxy10 * z0; w8[5] = wxy10 * wz;
    w8[6] = wxy11 * z0; w8[7] = wxy11 * wz;

    float dsum = 0.0f;
    float o0 = 0.0f, o1 = 0.0f, o2 = 0.0f;
    float e0 = 0.0f, e1 = 0.0f, e2 = 0.0f;

    const bool interior = active &&
        (ix >= 0) && (ix < kG - 1) &&
        (iy >= 0) && (iy < kG - 1) &&
        (iz >= 0) && (iz < kG - 1);
    const bool any = active && !interior &&
        (ix >= -1) && (ix <= kG - 1) &&
        (iy >= -1) && (iy <= kG - 1) &&
        (iz >= -1) && (iz <= kG - 1);

    if (interior) {
      const int base = (ix * kG + iy) * kG + iz;
      #pragma unroll
      for (int c = 0; c < 8; ++c) {
        const int gi = base + ((c >> 2) & 1) * kG2 + ((c >> 1) & 1) * kG + (c & 1);
        const float w = w8[c];
        const uint2 qa = packed2[(size_t)gi * 2];
        dsum = fmaf(w, bf_lo(qa.x), dsum);
        o0   = fmaf(w, bf_hi(qa.x), o0);
        o1   = fmaf(w, bf_lo(qa.y), o1);
        o2   = fmaf(w, bf_hi(qa.y), o2);
        if (on) {
          const uint2 qb = packed2[(size_t)gi * 2 + 1];
          e0 = fmaf(w, bf_lo(qb.x), e0);
          e1 = fmaf(w, bf_hi(qb.x), e1);
          e2 = fmaf(w, bf_lo(qb.y), e2);
        }
      }
    } else if (any) {
      #pragma unroll
      for (int c = 0; c < 8; ++c) {
        const int cx = ix + ((c >> 2) & 1);
        const int cy = iy + ((c >> 1) & 1);
        const int cz = iz + (c & 1);
        const bool valid = ((unsigned)cx < (unsigned)kG) &
                           ((unsigned)cy < (unsigned)kG) &
                           ((unsigned)cz < (unsigned)kG);
        const float wv = valid ? w8[c] : 0.0f;
        const int gx = min(max(cx, 0), kG - 1);
        const int gy = min(max(cy, 0), kG - 1);
        const int gz = min(max(cz, 0), kG - 1);
        const int gi = (gx * kG + gy) * kG + gz;
        const uint2 qa = packed2[(size_t)gi * 2];
        dsum = fmaf(wv, bf_lo(qa.x), dsum);
        o0   = fmaf(wv, bf_hi(qa.x), o0);
        o1   = fmaf(wv, bf_lo(qa.y), o1);
        o2   = fmaf(wv, bf_hi(qa.y), o2);
        if (on) {
          const uint2 qb = packed2[(size_t)gi * 2 + 1];
          e0 = fmaf(wv, bf_lo(qb.x), e0);
          e1 = fmaf(wv, bf_hi(qb.x), e1);
          e2 = fmaf(wv, bf_lo(qb.y), e2);
        }
      }
    }

    float alpha = 0.0f;
    if (active && !masked) {
      const float x  = dsum + kActShift;
      const float sp = fmaxf(x, 0.0f) + log1pf(expf(-fabsf(x)));
      alpha = 1.0f - expf(-sp * 0.5f);
    }
    float p = fmaxf(1.0f - alpha, 1e-10f);
    if (!active) p = 1.0f;

    // wave-wide inclusive prefix product
    float incl = p;
    #pragma unroll
    for (int o = 1; o < 64; o <<= 1) {
      const float n = __shfl_up(incl, o, 64);
      if (lane >= o) incl *= n;
    }
    float excl = __shfl_up(incl, 1, 64);
    if (lane == 0) excl = 1.0f;
    const float ainv_prev = carry * excl;
    const float ainv_next = carry * incl;
    const float wgt = alpha * ainv_prev;
    carry *= __shfl(incl, 63, 64);

    float rr = sigmoidf_(o0);
    float gg = sigmoidf_(o1);
    float bb = sigmoidf_(o2);
    if (on) {
      rr += sigmoidf_(e0);
      gg += sigmoidf_(e1);
      bb += sigmoidf_(e2);
    }

    if (active) {
      out_ainv[(size_t)ray * (kS + 1) + s + 1] = ainv_next;
      out_w[(size_t)ray * kS + s] = wgt;
      const size_t rb = ((size_t)ray * kS + s) * 3;
      out_rgb[rb + 0] = rr;
      out_rgb[rb + 1] = gg;
      out_rgb[rb + 2] = bb;
      accr = fmaf(wgt, rr, accr);
      accg = fmaf(wgt, gg, accg);
      accb = fmaf(wgt, bb, accb);
    }
  }

  #pragma unroll
  for (int o = 32; o > 0; o >>= 1) {
    accr += __shfl_xor(accr, o, 64);
    accg += __shfl_xor(accg, o, 64);
    accb += __shfl_xor(accb, o, 64);
  }
  if (lane == 0) {
    out_last[ray] = carry;
    out_rm[(size_t)ray * 3 + 0] = accr;
    out_rm[(size_t)ray * 3 + 1] = accg;
    out_rm[(size_t)ray * 3 + 2] = accb;
  }
}

extern "C" void kernel_launch(void* const* d_in, const int* in_sizes, int n_in,
                              void* d_out, int out_size, void* d_ws, size_t ws_size,
                              hipStream_t stream) {
  const float* rays_o  = (const float*)d_in[0];
  const float* rays_d  = (const float*)d_in[1];
  const float* jitter  = (const float*)d_in[2];
  const int*   em      = (const int*)d_in[3];
  const float* density = (const float*)d_in[4];
  const float* off_c   = (const float*)d_in[5];
  const float* emo_c   = (const float*)d_in[6];
  float* out = (float*)d_out;

  uint4* packed = (uint4*)d_ws;  // kPackedBytes = 65.5 MB, ws is larger
  (void)ws_size;

  hipLaunchKernelGGL(repack_grids, dim3((kG3 + 255) / 256), dim3(256), 0,
                     stream, density, off_c, emo_c, packed);

  const int threads = 256;
  const int blocks  = (kR * 64) / threads;  // 2048
  hipLaunchKernelGGL(dvgo_fwd, dim3(blocks), dim3(threads), 0, stream,
                     rays_o, rays_d, jitter, em, (const uint2*)packed, out);
}